// Round 8
// baseline (116.568 us; speedup 1.0000x reference)
//
#include <hip/hip_runtime.h>
#include <math.h>

#define BB 8
#define NN 512
#define DD 512
#define DKK 64
#define NC 192                  // 3*DK
#define CHN (BB * DKK * NN)     // floats per Q (or K or V) image
#define XEL (BB * NN * DD)      // 2097152 floats in X
#define WEL (NC * DD)           // 98304 floats in W_qkv

// (1/sqrt(64)) * log2(e) : fold softmax scale into exp2 domain
#define T_FACT 0.18033688011112042591999058f

#if defined(__has_builtin)
#if __has_builtin(__builtin_amdgcn_exp2f)
#define EXP2F(x) __builtin_amdgcn_exp2f(x)
#else
#define EXP2F(x) exp2f(x)
#endif
#else
#define EXP2F(x) exp2f(x)
#endif

typedef short s8v   __attribute__((ext_vector_type(8)));
typedef float f32x4 __attribute__((ext_vector_type(4)));
typedef unsigned short ushort;

static __device__ __forceinline__ ushort bf16_rne(float f) {
    unsigned u = __float_as_uint(f);
    unsigned r = 0x7FFFu + ((u >> 16) & 1u);
    return (ushort)((u + r) >> 16);
}
static __device__ __forceinline__ float bf16_f32(ushort h) {
    return __uint_as_float(((unsigned)h) << 16);
}

// -------------------------------------------------------------------------
// Kernel 0 (prep): split-bf16 pre-layout.
//  blocks [0,1024):  X (fp32, row-major) -> Xh/Xl bf16 [4096][512]
//  blocks [1024,1408): W (fp32 [k][3*DK]) -> Wth/Wtl bf16 transposed
//                      [wc][k] with wc = which*64+c  (k-contiguous rows)
// -------------------------------------------------------------------------
__global__ __launch_bounds__(256) void prep(const float* __restrict__ X,
                                            const float* __restrict__ W,
                                            ushort* __restrict__ Xh,
                                            ushort* __restrict__ Xl,
                                            ushort* __restrict__ Wth,
                                            ushort* __restrict__ Wtl) {
    const int tid = threadIdx.x;
    if (blockIdx.x < 1024) {
        // X: 524288 float4s, 2 per thread
        const size_t i0 = (size_t)blockIdx.x * 256 + tid;
        #pragma unroll
        for (int r = 0; r < 2; ++r) {
            const size_t i = i0 + (size_t)r * 262144;
            const float4 x = ((const float4*)X)[i];
            const float xe[4] = {x.x, x.y, x.z, x.w};
            ushort h[4], l[4];
            #pragma unroll
            for (int e = 0; e < 4; ++e) {
                h[e] = bf16_rne(xe[e]);
                l[e] = bf16_rne(xe[e] - bf16_f32(h[e]));
            }
            *(ushort4*)(Xh + 4 * i) = make_ushort4(h[0], h[1], h[2], h[3]);
            *(ushort4*)(Xl + 4 * i) = make_ushort4(l[0], l[1], l[2], l[3]);
        }
    } else {
        // W transpose: idx -> (wc, k)
        const int idx = (blockIdx.x - 1024) * 256 + tid;  // < 98304
        const int wc = idx >> 9;        // 0..191
        const int k  = idx & 511;
        const float w = W[(size_t)k * NC + wc];
        const ushort h = bf16_rne(w);
        const ushort l = bf16_rne(w - bf16_f32(h));
        Wth[(size_t)wc * DD + k] = h;
        Wtl[(size_t)wc * DD + k] = l;
    }
}

// -------------------------------------------------------------------------
// Kernel 1: QKV = X @ W on the MFMA pipe, split-bf16 (C ~= XhWh+XhWl+XlWh).
// NO LDS, NO barriers: every fragment is a 16-B global load from the
// prepped bf16 arrays (L2-resident). Grid (128 row-tiles, 3 which),
// 256 threads = 4 waves; wave = 16 seq x 32 chan.
// Fragment layouts (HW-verified m89/m91): A[m=lane&15][k=quad*8+j],
// B[n=lane&15][k=quad*8+j], C/D col(n)=lane&15, row(m)=quad*4+reg.
// Direct channel-major store: qkv[which][b][c][seq] as float4 per acc.
// -------------------------------------------------------------------------
__global__ __launch_bounds__(256) void qkv_mfma(const ushort* __restrict__ Xh,
                                                const ushort* __restrict__ Xl,
                                                const ushort* __restrict__ Wth,
                                                const ushort* __restrict__ Wtl,
                                                float* __restrict__ qkv) {
    const int tid   = threadIdx.x;
    const int row0  = blockIdx.x * 32;   // seq rows (b*n flattened)
    const int which = blockIdx.y;

    const int wid  = tid >> 6;           // 0..3
    const int lane = tid & 63;
    const int m0   = (wid >> 1) * 16;    // 0 / 16
    const int n0w  = (wid & 1) * 32;     // 0 / 32
    const int lm   = lane & 15;
    const int quad = lane >> 4;

    const ushort* xh = Xh + (size_t)(row0 + m0 + lm) * DD + quad * 8;
    const ushort* xl = Xl + (size_t)(row0 + m0 + lm) * DD + quad * 8;
    const ushort* wh = Wth + ((size_t)(which * 64 + n0w + lm)) * DD + quad * 8;
    const ushort* wl = Wtl + ((size_t)(which * 64 + n0w + lm)) * DD + quad * 8;

    f32x4 acc0 = {0.f, 0.f, 0.f, 0.f};
    f32x4 acc1 = {0.f, 0.f, 0.f, 0.f};

    #pragma unroll 4
    for (int ks = 0; ks < 16; ++ks) {
        const int ko = ks * 32;
        const s8v ah  = *(const s8v*)(xh + ko);
        const s8v al  = *(const s8v*)(xl + ko);
        const s8v bh0 = *(const s8v*)(wh + ko);
        const s8v bl0 = *(const s8v*)(wl + ko);
        const s8v bh1 = *(const s8v*)(wh + 16 * DD + ko);
        const s8v bl1 = *(const s8v*)(wl + 16 * DD + ko);
        acc0 = __builtin_amdgcn_mfma_f32_16x16x32_bf16(ah, bh0, acc0, 0, 0, 0);
        acc1 = __builtin_amdgcn_mfma_f32_16x16x32_bf16(ah, bh1, acc1, 0, 0, 0);
        acc0 = __builtin_amdgcn_mfma_f32_16x16x32_bf16(ah, bl0, acc0, 0, 0, 0);
        acc1 = __builtin_amdgcn_mfma_f32_16x16x32_bf16(ah, bl1, acc1, 0, 0, 0);
        acc0 = __builtin_amdgcn_mfma_f32_16x16x32_bf16(al, bh0, acc0, 0, 0, 0);
        acc1 = __builtin_amdgcn_mfma_f32_16x16x32_bf16(al, bh1, acc1, 0, 0, 0);
    }

    // store channel-major: c = n0w + t*16 + lm, seq = row0 + m0 + quad*4 + r
    const int b    = row0 >> 9;
    const int n0g  = row0 & 511;
    const int seq0 = n0g + m0 + quad * 4;
    float* base = qkv + (size_t)which * CHN + (size_t)b * DKK * NN;
    const float4 v0 = {acc0[0], acc0[1], acc0[2], acc0[3]};
    const float4 v1 = {acc1[0], acc1[1], acc1[2], acc1[3]};
    *(float4*)(base + (size_t)(n0w + lm) * NN + seq0)      = v0;
    *(float4*)(base + (size_t)(n0w + 16 + lm) * NN + seq0) = v1;
}

// -------------------------------------------------------------------------
// Kernel 2: per-(b,c) rank-1 softmax attention. 512 blocks (one per
// channel), 256 threads, 2 n per thread. Stable max via block-reduced
// kmax/kmin (M = t*kmax if t>0 else t*kmin).
// -------------------------------------------------------------------------
__global__ __launch_bounds__(256) void attn(const float* __restrict__ qkv,
                                            float* __restrict__ sa_t) {
    __shared__ float kl[NN];
    __shared__ float vl[NN];
    __shared__ float rmax[4], rmin[4];

    const int tid = threadIdx.x;
    const size_t chan = (size_t)blockIdx.x * NN;
    const float* qp = qkv + chan;
    const float* kp = qkv + CHN + chan;
    const float* vp = qkv + 2 * CHN + chan;

    if (tid < 128) ((float4*)kl)[tid]       = ((const float4*)kp)[tid];
    else           ((float4*)vl)[tid - 128] = ((const float4*)vp)[tid - 128];
    __syncthreads();

    float mx = fmaxf(kl[tid], kl[tid + 256]);
    float mn = fminf(kl[tid], kl[tid + 256]);
    #pragma unroll
    for (int off = 32; off > 0; off >>= 1) {
        mx = fmaxf(mx, __shfl_down(mx, off, 64));
        mn = fminf(mn, __shfl_down(mn, off, 64));
    }
    if ((tid & 63) == 0) { rmax[tid >> 6] = mx; rmin[tid >> 6] = mn; }
    __syncthreads();
    const float kmax = fmaxf(fmaxf(rmax[0], rmax[1]), fmaxf(rmax[2], rmax[3]));
    const float kmin = fminf(fminf(rmin[0], rmin[1]), fminf(rmin[2], rmin[3]));

    const float t0 = qp[tid] * T_FACT;
    const float t1 = qp[tid + 256] * T_FACT;
    const float M0 = t0 > 0.f ? t0 * kmax : t0 * kmin;
    const float M1 = t1 > 0.f ? t1 * kmax : t1 * kmin;

    float sw0 = 0.f, sv0 = 0.f, sw1 = 0.f, sv1 = 0.f;
    const float4* k4 = (const float4*)kl;
    const float4* v4 = (const float4*)vl;
    #pragma unroll 2
    for (int j = 0; j < NN / 4; ++j) {
        const float4 kk = k4[j];
        const float4 vv = v4[j];
        const float ke[4] = {kk.x, kk.y, kk.z, kk.w};
        const float ve[4] = {vv.x, vv.y, vv.z, vv.w};
        #pragma unroll
        for (int e = 0; e < 4; ++e) {
            const float w0 = EXP2F(fmaf(t0, ke[e], -M0));
            sw0 += w0;
            sv0 = fmaf(w0, ve[e], sv0);
            const float w1 = EXP2F(fmaf(t1, ke[e], -M1));
            sw1 += w1;
            sv1 = fmaf(w1, ve[e], sv1);
        }
    }
    sa_t[chan + tid]       = sv0 / sw0;
    sa_t[chan + tid + 256] = sv1 / sw1;
}

// -------------------------------------------------------------------------
// Kernel 3: out = SA(4096x64) @ Wo(64x512). sa_t is [b][c][n] (K-major
// per b). 256 threads, 64x64 tile, 4x4 micro-tile, float4 stores.
// -------------------------------------------------------------------------
__global__ __launch_bounds__(256) void out_gemm(const float* __restrict__ sa_t,
                                                const float* __restrict__ Wo,
                                                float* __restrict__ out) {
    __shared__ float As[64][68];  // As[c][n_local]
    __shared__ float Bs[64][68];  // Bs[c][d_local]

    const int tid  = threadIdx.x;
    const int row0 = blockIdx.x * 64;
    const int d0   = blockIdx.y * 64;
    const int b    = row0 >> 9;
    const int n0   = row0 & 511;

    const int f  = tid & 15;   // float4 index within 64
    const int r0 = tid >> 4;   // 0..15
    #pragma unroll
    for (int rr = 0; rr < 4; ++rr) {
        const int cidx = r0 + rr * 16;
        *(float4*)&As[cidx][4 * f] =
            *(const float4*)(sa_t + (size_t)(b * DKK + cidx) * NN + n0 + 4 * f);
        *(float4*)&Bs[cidx][4 * f] =
            *(const float4*)(Wo + (size_t)cidx * DD + d0 + 4 * f);
    }
    __syncthreads();

    const int tc = tid & 15;
    const int tr = tid >> 4;
    float acc[4][4] = {};
    #pragma unroll 8
    for (int k = 0; k < DKK; ++k) {
        const float4 a  = *(const float4*)&As[k][4 * tr];
        const float4 bv = *(const float4*)&Bs[k][4 * tc];
        const float av[4] = {a.x, a.y, a.z, a.w};
        const float be[4] = {bv.x, bv.y, bv.z, bv.w};
        #pragma unroll
        for (int i = 0; i < 4; ++i)
            #pragma unroll
            for (int j = 0; j < 4; ++j)
                acc[i][j] = fmaf(av[i], be[j], acc[i][j]);
    }

    float* op = out + ((size_t)(b * NN + n0)) * DD + d0;
    #pragma unroll
    for (int i = 0; i < 4; ++i) {
        const float4 v = {acc[i][0], acc[i][1], acc[i][2], acc[i][3]};
        *(float4*)(op + (size_t)(4 * tr + i) * DD + 4 * tc) = v;
    }
}

extern "C" void kernel_launch(void* const* d_in, const int* in_sizes, int n_in,
                              void* d_out, int out_size, void* d_ws, size_t ws_size,
                              hipStream_t stream) {
    const float* X    = (const float*)d_in[0];  // (8,512,512)
    const float* Wqkv = (const float*)d_in[1];  // (512,192)
    const float* Wo   = (const float*)d_in[2];  // (64,512)
    float* out = (float*)d_out;                 // (8,512,512)

    // ws layout (16B-aligned chunks):
    float*  qkv  = (float*)d_ws;                        // 3 MB
    float*  sa_t = qkv + (size_t)3 * CHN;               // 1 MB
    ushort* Xh   = (ushort*)(sa_t + CHN);               // 4 MB
    ushort* Xl   = Xh + (size_t)XEL;                    // 4 MB
    ushort* Wth  = Xl + (size_t)XEL;                    // 192 KB
    ushort* Wtl  = Wth + (size_t)WEL;                   // 192 KB

    prep<<<dim3(1024 + 384), 256, 0, stream>>>(X, Wqkv, Xh, Xl, Wth, Wtl);
    qkv_mfma<<<dim3(128, 3), 256, 0, stream>>>(Xh, Xl, Wth, Wtl, qkv);
    attn<<<dim3(BB * DKK), 256, 0, stream>>>(qkv, sa_t);
    out_gemm<<<dim3(64, 8), 256, 0, stream>>>(sa_t, Wo, out);
}